// Round 11
// baseline (157.512 us; speedup 1.0000x reference)
//
#include <hip/hip_runtime.h>

#define DD 8
#define HW 16384
#define KK 256
#define NPIX 524288
#define NBLK 2048                      // 256 px per block, 4 groups x 64 px, 4 thr/px

#define Y_OFF    4194304UL             // B*D*H*W
#define REP_OFF  4718592UL             // + B*H*W
#define LOSS_OFF 138936320UL           // + B*H*W*K

typedef float f4 __attribute__((ext_vector_type(4)));

// ---------------- prep: zero hist (1 KB) ----------------
// (kept as hipMemsetAsync in kernel_launch)

// ---- fused: 4-deep wave-independent pipeline, 4 threads per pixel ----
__global__ __launch_bounds__(256) void vq_fused_kernel(
    const float* __restrict__ q, const float* __restrict__ cb,
    float* __restrict__ emb, float* __restrict__ yf, float* __restrict__ rep,
    int* __restrict__ hist, float* __restrict__ partial)
{
    __shared__ float sc2[KK];
    __shared__ int   sy[4][16];        // per-wave current-group row codes
    __shared__ int   shist[KK];
    __shared__ float swred[4];

    const int tid  = threadIdx.x;
    const int wid  = tid >> 6;
    const int lane = tid & 63;
    const int slot = lane & 15;        // pixel slot within wave-group
    const int r    = lane >> 4;        // code-range index 0..3
    shist[tid] = 0;

    {   // ||c||^2 (same expression/bits as prior rounds)
        const f4 c01 = *(const f4*)(cb + tid*8);
        const f4 c23 = *(const f4*)(cb + tid*8 + 4);
        sc2[tid] = ((c01.x*c01.x + c01.y*c01.y) + (c01.z*c01.z + c01.w*c01.w))
                 + ((c23.x*c23.x + c23.y*c23.y) + (c23.z*c23.z + c23.w*c23.w));
    }

    const int pixBase = blockIdx.x << 8;     // 256 consecutive pixels, one image
    const int b   = pixBase >> 14;
    const int hw0 = pixBase & (HW - 1);
    const float* qb = q + (size_t)b * (DD*HW);
    float* eb = emb + (size_t)b * (DD*HW);

    // preload all 4 groups' pixel (4 lanes share a pixel -> broadcast loads)
    float xs[4][DD];
    float xn[4];
#pragma unroll
    for (int g = 0; g < 4; ++g) {
        const int hw = hw0 + (g << 6) + (wid << 4) + slot;
#pragma unroll
        for (int d = 0; d < DD; ++d) xs[g][d] = qb[d*HW + hw];
        xn[g] = ((xs[g][0]*xs[g][0] + xs[g][1]*xs[g][1]) + (xs[g][2]*xs[g][2] + xs[g][3]*xs[g][3]))
              + ((xs[g][4]*xs[g][4] + xs[g][5]*xs[g][5]) + (xs[g][6]*xs[g][6] + xs[g][7]*xs[g][7]));
    }

    __syncthreads();   // sc2 + shist ready (no stores in flight yet)

    float err = 0.f;
    const int b4 = lane << 2;
    const int k0 = r << 6;             // this thread's code range [k0, k0+64)

#pragma unroll
    for (int g = 0; g < 4; ++g) {
        // scan 64 codes, interleaved with streaming group g-1's 16 rows
        float best = 3.4e38f;
        int   yb   = 0;
        for (int c = 0; c < 16; ++c) {
#pragma unroll
            for (int j = 0; j < 4; ++j) {
                const int k = k0 + (c << 2) + j;
                const f4 c01 = *(const f4*)(cb + (k << 3));   // lane-varies only by r
                const f4 c23 = *(const f4*)(cb + (k << 3) + 4);
                const float c2k = sc2[k];
                float dot = 0.f;
                dot = fmaf(xs[g][0], c01.x, dot);
                dot = fmaf(xs[g][1], c01.y, dot);
                dot = fmaf(xs[g][2], c01.z, dot);
                dot = fmaf(xs[g][3], c01.w, dot);
                dot = fmaf(xs[g][4], c23.x, dot);
                dot = fmaf(xs[g][5], c23.y, dot);
                dot = fmaf(xs[g][6], c23.z, dot);
                dot = fmaf(xs[g][7], c23.w, dot);
                const float t = (xn[g] - 2.0f*dot) + c2k;
                if (t < best) { best = t; yb = k; }   // earliest k in range wins ties
            }
            if (g > 0) {
                // stream one row of group g-1 (own-wave sy, folded 1.0, nt)
                const int ya = sy[wid][c];
                f4 v;
                v.x = (ya == b4    ) ? 1.0f : 0.0f;
                v.y = (ya == b4 + 1) ? 1.0f : 0.0f;
                v.z = (ya == b4 + 2) ? 1.0f : 0.0f;
                v.w = (ya == b4 + 3) ? 1.0f : 0.0f;
                f4* rp = (f4*)rep + (((size_t)(pixBase + ((g - 1) << 6) + (wid << 4) + c)) << 6) + lane;
                __builtin_nontemporal_store(v, rp);
            }
        }

        // combine the 4 code-ranges: min t, smaller k on ties (== reference
        // first-index-wins over the ascending scan)
        {
            float t2 = __shfl_xor(best, 16, 64);
            int   y2 = __shfl_xor(yb,   16, 64);
            if (t2 < best || (t2 == best && y2 < yb)) { best = t2; yb = y2; }
            t2 = __shfl_xor(best, 32, 64);
            y2 = __shfl_xor(yb,   32, 64);
            if (t2 < best || (t2 == best && y2 < yb)) { best = t2; yb = y2; }
        }

        // per-pixel outputs by the r==0 lane of each quad
        if (r == 0) {
            const int px = (g << 6) + (wid << 4) + slot;
            const int hw = hw0 + px;
            const f4 cy01 = *(const f4*)(cb + (yb << 3));
            const f4 cy23 = *(const f4*)(cb + (yb << 3) + 4);
            const float cyv[DD] = {cy01.x, cy01.y, cy01.z, cy01.w,
                                   cy23.x, cy23.y, cy23.z, cy23.w};
#pragma unroll
            for (int d = 0; d < DD; ++d) {
                eb[d*HW + hw] = cyv[d];
                const float dd = cyv[d] - xs[g][d];
                err = fmaf(dd, dd, err);
            }
            yf[pixBase + px] = (float)yb;
            sy[wid][slot] = yb;           // own-wave; read next group iteration
            atomicAdd(&shist[yb], 1);
        }
    }

    // final stream: group 3's 16 rows
    for (int c = 0; c < 16; ++c) {
        const int ya = sy[wid][c];
        f4 v;
        v.x = (ya == b4    ) ? 1.0f : 0.0f;
        v.y = (ya == b4 + 1) ? 1.0f : 0.0f;
        v.z = (ya == b4 + 2) ? 1.0f : 0.0f;
        v.w = (ya == b4 + 3) ? 1.0f : 0.0f;
        f4* rp = (f4*)rep + (((size_t)(pixBase + 192 + (wid << 4) + c)) << 6) + lane;
        __builtin_nontemporal_store(v, rp);
    }

    // deterministic wave reduction of err (r>0 lanes contribute 0)
#pragma unroll
    for (int off = 32; off; off >>= 1)
        err += __shfl_down(err, off, 64);
    if (lane == 0) swred[wid] = err;
    __syncthreads();
    if (tid == 0)
        partial[blockIdx.x] = (swred[0] + swred[1]) + (swred[2] + swred[3]);
    atomicAdd(&hist[tid], shist[tid]);   // shist complete after barrier above
}

// ---------------- finalize scalars ----------------
__global__ __launch_bounds__(256) void vq_final_kernel(
    const float* __restrict__ partial, const int* __restrict__ hist,
    float* __restrict__ outp)
{
    const int tid = threadIdx.x;
    __shared__ double sred[4];
    __shared__ double shy[4];

    double s = 0.0;
#pragma unroll
    for (int i = 0; i < 8; ++i) s += (double)partial[tid * 8 + i];
#pragma unroll
    for (int off = 32; off; off >>= 1)
        s += __shfl_down(s, off, 64);
    if ((tid & 63) == 0) sred[tid >> 6] = s;

    float c  = (float)hist[tid];
    float py = c * (1.0f / 524288.0f);
    double ht = (double)(py * log2f(py + 1e-10f));
#pragma unroll
    for (int off = 32; off; off >>= 1)
        ht += __shfl_down(ht, off, 64);
    if ((tid & 63) == 0) shy[tid >> 6] = ht;
    __syncthreads();

    if (tid == 0) {
        double S  = (sred[0] + sred[1]) + (sred[2] + sred[3]);
        double Hy = (shy[0]  + shy[1])  + (shy[2]  + shy[3]);
        // loss = 0.5*(0.25*S/4096 + S/4096) = 0.625 * S / 4096
        outp[0] = (float)(0.625 * S / 4096.0);
        outp[1] = (float)(-Hy);
        outp[2] = 0.0f;
    }
}

extern "C" void kernel_launch(void* const* d_in, const int* in_sizes, int n_in,
                              void* d_out, int out_size, void* d_ws, size_t ws_size,
                              hipStream_t stream)
{
    const float* q  = (const float*)d_in[0];
    const float* cb = (const float*)d_in[1];
    float* out = (float*)d_out;

    float* emb = out;                     // [B,D,H,W]
    float* yf  = out + Y_OFF;             // [B,H,W] as float
    float* rep = out + REP_OFF;           // [B,H,W,K]
    float* sc  = out + LOSS_OFF;          // loss, Hy, Hyx

    float* w       = (float*)d_ws;
    int*   hist    = (int*)w;             // 256 ints
    float* partial = w + 256;             // 2048 floats

    hipMemsetAsync(hist, 0, 1024, stream);   // zero hist
    vq_fused_kernel<<<NBLK, 256, 0, stream>>>(q, cb, emb, yf, rep, hist, partial);
    vq_final_kernel<<<1, 256, 0, stream>>>(partial, hist, sc);
}

// Round 12
// 124.387 us; speedup vs baseline: 1.2663x; 1.2663x over previous
//
#include <hip/hip_runtime.h>

#define DD 8
#define HW 16384
#define KK 256
#define NPIX 524288
#define NBLK 1024                      // 512 px per block, 2 px/thread (A/B)

#define Y_OFF    4194304UL             // B*D*H*W
#define REP_OFF  4718592UL             // + B*H*W
#define LOSS_OFF 138936320UL           // + B*H*W*K

typedef float f4 __attribute__((ext_vector_type(4)));

// LDS-only barrier: orders LDS (lgkmcnt) across waves WITHOUT draining the
// nt-store queue (vmcnt) — in-flight one-hot stores keep streaming.
__device__ __forceinline__ void lds_barrier() {
    asm volatile("s_waitcnt lgkmcnt(0)\n\ts_barrier" ::: "memory");
}

// ---- fused: free-running waves — compute A, then B-compute ∥ A-stream, then B-stream ----
__global__ __launch_bounds__(256) void vq_fused_kernel(
    const float* __restrict__ q, const float* __restrict__ cb,
    float* __restrict__ emb, float* __restrict__ yf, float* __restrict__ rep,
    int* __restrict__ hist, float* __restrict__ partial)
{
    __shared__ float sc2[KK];
    __shared__ int   syA[256];
    __shared__ int   syB[256];
    __shared__ int   shist[KK];
    __shared__ float swred[4];

    const int tid  = threadIdx.x;
    const int wid  = tid >> 6;
    const int lane = tid & 63;
    shist[tid] = 0;

    {   // ||c||^2 in-block (same expression/bits as prior rounds)
        const f4 c01 = *(const f4*)(cb + tid*8);
        const f4 c23 = *(const f4*)(cb + tid*8 + 4);
        sc2[tid] = ((c01.x*c01.x + c01.y*c01.y) + (c01.z*c01.z + c01.w*c01.w))
                 + ((c23.x*c23.x + c23.y*c23.y) + (c23.z*c23.z + c23.w*c23.w));
    }

    const int pixBase = blockIdx.x << 9;     // 512 consecutive pixels, one image
    const int b    = pixBase >> 14;
    const int hw0  = pixBase & (HW - 1);
    const int hwA  = hw0 + tid;
    const int hwB2 = hw0 + 256 + tid;
    const float* qb = q + (size_t)b * (DD*HW);
    float* eb = emb + (size_t)b * (DD*HW);

    float xsA[DD], xsB[DD];
#pragma unroll
    for (int d = 0; d < DD; ++d) xsA[d] = qb[d*HW + hwA];
#pragma unroll
    for (int d = 0; d < DD; ++d) xsB[d] = qb[d*HW + hwB2];

    const float xnA = ((xsA[0]*xsA[0] + xsA[1]*xsA[1]) + (xsA[2]*xsA[2] + xsA[3]*xsA[3]))
                    + ((xsA[4]*xsA[4] + xsA[5]*xsA[5]) + (xsA[6]*xsA[6] + xsA[7]*xsA[7]));
    const float xnB = ((xsB[0]*xsB[0] + xsB[1]*xsB[1]) + (xsB[2]*xsB[2] + xsB[3]*xsB[3]))
                    + ((xsB[4]*xsB[4] + xsB[5]*xsB[5]) + (xsB[6]*xsB[6] + xsB[7]*xsB[7]));

    __syncthreads();   // sc2 + shist ready (no stores in flight yet)

    // ---- phase 1: argmax A (t = (x2-2xc)+c2, strict <  ==  ref -0.5*t, strict >) ----
    float bestA = 3.4e38f;
    int   yA    = 0;
#pragma unroll 4
    for (int k = 0; k < KK; ++k) {
        const f4 c01 = *(const f4*)(cb + (k << 3));   // lane-invariant -> s_load
        const f4 c23 = *(const f4*)(cb + (k << 3) + 4);
        const float c2k = sc2[k];
        float dot = 0.f;
        dot = fmaf(xsA[0], c01.x, dot);
        dot = fmaf(xsA[1], c01.y, dot);
        dot = fmaf(xsA[2], c01.z, dot);
        dot = fmaf(xsA[3], c01.w, dot);
        dot = fmaf(xsA[4], c23.x, dot);
        dot = fmaf(xsA[5], c23.y, dot);
        dot = fmaf(xsA[6], c23.z, dot);
        dot = fmaf(xsA[7], c23.w, dot);
        const float t = (xnA - 2.0f*dot) + c2k;
        if (t < bestA) { bestA = t; yA = k; }
    }

    float err = 0.f;
    {
        const f4 cy01 = *(const f4*)(cb + (yA << 3));
        const f4 cy23 = *(const f4*)(cb + (yA << 3) + 4);
        const float cyv[DD] = {cy01.x, cy01.y, cy01.z, cy01.w,
                               cy23.x, cy23.y, cy23.z, cy23.w};
#pragma unroll
        for (int d = 0; d < DD; ++d) {
            eb[d*HW + hwA] = cyv[d];
            const float dd = cyv[d] - xsA[d];
            err = fmaf(dd, dd, err);
        }
    }
    yf[pixBase + tid] = (float)yA;
    syA[tid] = yA;                      // read back only by THIS wave — no barrier
    atomicAdd(&shist[yA], 1);

    // ---- phase 2: argmax B interleaved with A's folded one-hot streaming ----
    float bestB = 3.4e38f;
    int   yB    = 0;
    f4* repA = (f4*)rep + (((size_t)(pixBase + (wid << 6))) << 6) + lane;
    const int b4 = lane << 2;
    for (int c = 0; c < 64; ++c) {
#pragma unroll
        for (int j = 0; j < 4; ++j) {
            const int k = (c << 2) + j;
            const f4 c01 = *(const f4*)(cb + (k << 3));
            const f4 c23 = *(const f4*)(cb + (k << 3) + 4);
            const float c2k = sc2[k];
            float dot = 0.f;
            dot = fmaf(xsB[0], c01.x, dot);
            dot = fmaf(xsB[1], c01.y, dot);
            dot = fmaf(xsB[2], c01.z, dot);
            dot = fmaf(xsB[3], c01.w, dot);
            dot = fmaf(xsB[4], c23.x, dot);
            dot = fmaf(xsB[5], c23.y, dot);
            dot = fmaf(xsB[6], c23.z, dot);
            dot = fmaf(xsB[7], c23.w, dot);
            const float t = (xnB - 2.0f*dot) + c2k;
            if (t < bestB) { bestB = t; yB = k; }
        }
        const int ya = syA[(wid << 6) + c];   // own-wave LDS broadcast
        f4 v;
        v.x = (ya == b4    ) ? 1.0f : 0.0f;
        v.y = (ya == b4 + 1) ? 1.0f : 0.0f;
        v.z = (ya == b4 + 2) ? 1.0f : 0.0f;
        v.w = (ya == b4 + 3) ? 1.0f : 0.0f;
        __builtin_nontemporal_store(v, repA + ((size_t)c << 6));
    }

    {
        const f4 cy01 = *(const f4*)(cb + (yB << 3));
        const f4 cy23 = *(const f4*)(cb + (yB << 3) + 4);
        const float cyv[DD] = {cy01.x, cy01.y, cy01.z, cy01.w,
                               cy23.x, cy23.y, cy23.z, cy23.w};
#pragma unroll
        for (int d = 0; d < DD; ++d) {
            eb[d*HW + hwB2] = cyv[d];
            const float dd = cyv[d] - xsB[d];
            err = fmaf(dd, dd, err);
        }
    }
    yf[pixBase + 256 + tid] = (float)yB;
    syB[tid] = yB;                      // own-wave only
    atomicAdd(&shist[yB], 1);

    // ---- phase 3: stream B's folded rows (own-wave sy, no barrier) ----
    {
        f4* repB = (f4*)rep + (((size_t)(pixBase + 256 + (wid << 6))) << 6) + lane;
        for (int c = 0; c < 64; ++c) {
            const int yb2 = syB[(wid << 6) + c];
            f4 v;
            v.x = (yb2 == b4    ) ? 1.0f : 0.0f;
            v.y = (yb2 == b4 + 1) ? 1.0f : 0.0f;
            v.z = (yb2 == b4 + 2) ? 1.0f : 0.0f;
            v.w = (yb2 == b4 + 3) ? 1.0f : 0.0f;
            __builtin_nontemporal_store(v, repB + ((size_t)c << 6));
        }
    }

    // deterministic wave reduction of err (both pixels)
#pragma unroll
    for (int off = 32; off; off >>= 1)
        err += __shfl_down(err, off, 64);
    if (lane == 0) swred[wid] = err;

    lds_barrier();   // shist atomics + swred visible; nt stores keep draining

    if (tid == 0)
        partial[blockIdx.x] = (swred[0] + swred[1]) + (swred[2] + swred[3]);
    atomicAdd(&hist[tid], shist[tid]);   // cheap: 256 ints, 1024 blocks
}

// ---------------- finalize scalars ----------------
__global__ __launch_bounds__(256) void vq_final_kernel(
    const float* __restrict__ partial, const int* __restrict__ hist,
    float* __restrict__ outp)
{
    const int tid = threadIdx.x;
    __shared__ double sred[4];
    __shared__ double shy[4];

    double s = 0.0;
#pragma unroll
    for (int i = 0; i < 4; ++i) s += (double)partial[tid + (i << 8)];
#pragma unroll
    for (int off = 32; off; off >>= 1)
        s += __shfl_down(s, off, 64);
    if ((tid & 63) == 0) sred[tid >> 6] = s;

    float c  = (float)hist[tid];
    float py = c * (1.0f / 524288.0f);
    double ht = (double)(py * log2f(py + 1e-10f));
#pragma unroll
    for (int off = 32; off; off >>= 1)
        ht += __shfl_down(ht, off, 64);
    if ((tid & 63) == 0) shy[tid >> 6] = ht;
    __syncthreads();

    if (tid == 0) {
        double S  = (sred[0] + sred[1]) + (sred[2] + sred[3]);
        double Hy = (shy[0]  + shy[1])  + (shy[2]  + shy[3]);
        // loss = 0.5*(0.25*S/4096 + S/4096) = 0.625 * S / 4096
        outp[0] = (float)(0.625 * S / 4096.0);
        outp[1] = (float)(-Hy);
        outp[2] = 0.0f;
    }
}

extern "C" void kernel_launch(void* const* d_in, const int* in_sizes, int n_in,
                              void* d_out, int out_size, void* d_ws, size_t ws_size,
                              hipStream_t stream)
{
    const float* q  = (const float*)d_in[0];
    const float* cb = (const float*)d_in[1];
    float* out = (float*)d_out;

    float* emb = out;                     // [B,D,H,W]
    float* yf  = out + Y_OFF;             // [B,H,W] as float
    float* rep = out + REP_OFF;           // [B,H,W,K]
    float* sc  = out + LOSS_OFF;          // loss, Hy, Hyx

    float* w       = (float*)d_ws;
    int*   hist    = (int*)w;             // 256 ints
    float* partial = w + 256;             // 1024 floats

    hipMemsetAsync(hist, 0, 1024, stream);   // zero hist
    vq_fused_kernel<<<NBLK, 256, 0, stream>>>(q, cb, emb, yf, rep, hist, partial);
    vq_final_kernel<<<1, 256, 0, stream>>>(partial, hist, sc);
}